// Round 15
// baseline (120.838 us; speedup 1.0000x reference)
//
#include <hip/hip_runtime.h>
#include <math.h>

// MaskedConvFlow — bf16 MFMA, 8-row strips, Ct double-buffered.
// R15 = R14 + GEMM1 wave-retile co(x4) × w(x2): halves GEMM1 ds_read_b128
// count (24 vs 48 per wave per row; the co-only split made all 8 waves read
// identical Xt fragments) at the cost of 2x A-fragment L2 loads (Wm repack
// is L2-resident; HBM FETCH unaffected). LDS-port cycles per row per CU:
// 6144 -> 3840, now below MFMA's 4128. Everything else = R14.
// (512,2) only; min_waves >= 3 hints are allocator poison (R4/R6/R7/R9).

#define BATCH 32
#define HDIM 64
#define WDIM 64
#define ROWS 8
#define STRIPS 8
#define NBLK (BATCH * STRIPS)   // 256
#define NSLOT 10                // input rows h0-2 .. h0+7
#define CT_LD 264               // 256 + 8 pad shorts (16B-aligned rows)

typedef __attribute__((ext_vector_type(8))) short short8;
typedef __attribute__((ext_vector_type(4))) float f32x4;

__device__ inline unsigned short f2bf(float f) {
    union { float f; unsigned int u; } v; v.f = f;
    unsigned int u = v.u;
    unsigned int r = u + 0x7FFFu + ((u >> 16) & 1u);   // RNE
    return (unsigned short)(r >> 16);
}

__device__ inline float bf2f(unsigned short s) {
    union { unsigned int u; float f; } v;
    v.u = ((unsigned int)s) << 16;
    return v.f;
}

// Xt element offset (shorts): chunk-XOR swizzle, conflict-free b128 reads
__device__ inline int xt_off(int slot, int wp, int ci) {
    return ((slot * 66 + wp) << 6) + ((((ci >> 3) ^ (wp & 7)) << 3) | (ci & 7));
}

// ---- prep: weight convert/repack ----
// WmR[((kh*3+kw)*256+co)*64+ci] = bf16(Wm[co][ci][kh][kw]); W1b[o][k] = bf16(W1)
__global__ __launch_bounds__(256) void mcf_prep(
    const float* __restrict__ Wm, const float* __restrict__ W1,
    unsigned short* __restrict__ WmR, unsigned short* __restrict__ W1b)
{
    int idx = blockIdx.x * 256 + threadIdx.x;     // grid covers 131072
    if (idx < 6 * 256 * 64) {
        int khkw = idx >> 14;
        int rem = idx & 16383;
        int co = rem >> 6;
        int ci = rem & 63;
        int kh = khkw / 3, kw = khkw % 3;
        WmR[idx] = f2bf(Wm[((co * 64 + ci) * 2 + kh) * 3 + kw]);
    } else {
        int i = idx - 6 * 256 * 64;
        W1b[i] = f2bf(W1[i]);
    }
}

__global__ __launch_bounds__(512, 2) void mcf_mfma(
    const float* __restrict__ x,
    const unsigned short* __restrict__ WmR,
    const float* __restrict__ bm,
    const unsigned short* __restrict__ W1b,
    const float* __restrict__ b1,
    float* __restrict__ out, float* __restrict__ row_ld)
{
    __shared__ __align__(16) unsigned short Xt[NSLOT * 66 * 64];  // 84480 B
    __shared__ __align__(16) unsigned short Ct[2][64 * CT_LD];    // 67584 B
    __shared__ float red[8];

    const int blk = blockIdx.x;
    const int b = blk >> 3;
    const int h0 = (blk & 7) * ROWS;
    const int tid = threadIdx.x;
    const int lane = tid & 63;
    const int wv = tid >> 6;        // 0..7
    const int col = lane & 15;
    const int g = lane >> 4;

    // ---- zero pad wp=0 / wp=65 for all slots (NSLOT*128 entries, STRIDED) ----
    for (int l = tid; l < NSLOT * 128; l += 512) {
        int s = l >> 7, rr = l & 127;
        int wp = (rr >= 64) ? 65 : 0, ci = rr & 63;
        Xt[xt_off(s, wp, ci)] = 0;
    }
    // ---- stage NSLOT input rows (h0-2..h0+7), paired-bf16 ----
    #pragma unroll 4
    for (int it = 0; it < NSLOT * 4; ++it) {
        int idx = it * 512 + tid;       // pair idx: 64 w * 32 ci2 * NSLOT slots
        int w = idx & 63;
        int ci = ((idx >> 6) & 31) * 2;
        int slot = idx >> 11;           // 0..NSLOT-1
        int row = h0 - 2 + slot;
        float v0 = 0.f, v1 = 0.f;
        if (row >= 0) {
            const float* base = &x[(((size_t)b * 64 + ci) * 64 + row) * 64 + w];
            v0 = base[0];
            v1 = base[64 * 64];         // ci+1
        }
        unsigned int pk = (unsigned int)f2bf(v0) | ((unsigned int)f2bf(v1) << 16);
        *reinterpret_cast<unsigned int*>(&Xt[xt_off(slot, w + 1, ci)]) = pk;
    }
    __syncthreads();

    const int coq = wv & 3;     // GEMM1 co-quarter (64 co)
    const int whf = wv >> 2;    // GEMM1 w-half (32 w)
    float ldacc = 0.f;

    #pragma unroll 1
    for (int r = 0; r < ROWS; ++r) {
        unsigned short* Cb = Ct[r & 1];

        // ---- GEMM1: co-quarter x w-half, acc[4][2] ----
        f32x4 acc[4][2];
        #pragma unroll
        for (int ct = 0; ct < 4; ++ct) {
            #pragma unroll
            for (int j = 0; j < 4; ++j) {
                float bv = bm[coq * 64 + ct * 16 + g * 4 + j];
                #pragma unroll
                for (int wt = 0; wt < 2; ++wt) acc[ct][wt][j] = bv;
            }
        }

        #pragma unroll
        for (int kh = 0; kh < 2; ++kh) {
            #pragma unroll
            for (int kw = 0; kw < 3; ++kw) {
                const unsigned short* wmk = WmR + ((kh * 3 + kw) << 14);
                #pragma unroll
                for (int ks = 0; ks < 2; ++ks) {
                    short8 bfrag[2];
                    #pragma unroll
                    for (int wt = 0; wt < 2; ++wt) {
                        int wp = whf * 32 + wt * 16 + col + kw;
                        bfrag[wt] = *reinterpret_cast<const short8*>(
                            &Xt[(((r + kh) * 66 + wp) << 6) + ((((ks * 4 + g) ^ (wp & 7)) << 3))]);
                    }
                    #pragma unroll
                    for (int ct = 0; ct < 4; ++ct) {
                        short8 af = *reinterpret_cast<const short8*>(
                            &wmk[(coq * 64 + ct * 16 + col) * 64 + ks * 32 + g * 8]);
                        #pragma unroll
                        for (int wt = 0; wt < 2; ++wt)
                            acc[ct][wt] = __builtin_amdgcn_mfma_f32_16x16x32_bf16(
                                af, bfrag[wt], acc[ct][wt], 0, 0, 0);
                    }
                }
            }
        }
        // relu -> bf16 -> Ct[w][co]
        #pragma unroll
        for (int ct = 0; ct < 4; ++ct) {
            int co_base = coq * 64 + ct * 16 + g * 4;
            #pragma unroll
            for (int wt = 0; wt < 2; ++wt) {
                int w = whf * 32 + wt * 16 + col;
                unsigned short pk[4];
                #pragma unroll
                for (int j = 0; j < 4; ++j) pk[j] = f2bf(fmaxf(acc[ct][wt][j], 0.f));
                *reinterpret_cast<unsigned long long*>(&Cb[w * CT_LD + co_base]) =
                    *reinterpret_cast<const unsigned long long*>(pk);
            }
        }
        __syncthreads();   // Ct[r&1] ready — only barrier this row

        // ---- GEMM2 + fused epilogue (row h0+r), unchanged from R14 ----
        {
            const int pr = wv & 3;      // mu row-tile (ls = pr+4)
            const int wcg = wv >> 2;    // w-tile group
            f32x4 accM[2], accL[2];
            #pragma unroll
            for (int j = 0; j < 4; ++j) {
                float bmu = b1[pr * 16 + g * 4 + j];
                float bls = b1[64 + pr * 16 + g * 4 + j];
                accM[0][j] = bmu; accM[1][j] = bmu;
                accL[0][j] = bls; accL[1][j] = bls;
            }
            #pragma unroll
            for (int ks = 0; ks < 8; ++ks) {
                int kk = ks * 32 + g * 8;
                short8 bf2[2];
                #pragma unroll
                for (int wt = 0; wt < 2; ++wt) {
                    int w = (wcg * 2 + wt) * 16 + col;
                    bf2[wt] = *reinterpret_cast<const short8*>(&Cb[w * CT_LD + kk]);
                }
                int oA = pr * 16 + col;
                short8 aM = *reinterpret_cast<const short8*>(&W1b[oA * 256 + kk]);
                short8 aL = *reinterpret_cast<const short8*>(&W1b[(oA + 64) * 256 + kk]);
                #pragma unroll
                for (int wt = 0; wt < 2; ++wt) {
                    accM[wt] = __builtin_amdgcn_mfma_f32_16x16x32_bf16(aM, bf2[wt], accM[wt], 0, 0, 0);
                    accL[wt] = __builtin_amdgcn_mfma_f32_16x16x32_bf16(aL, bf2[wt], accL[wt], 0, 0, 0);
                }
            }
            int h = h0 + r;
            float prod = 1.f;
            #pragma unroll
            for (int wt = 0; wt < 2; ++wt) {
                int w = (wcg * 2 + wt) * 16 + col;
                #pragma unroll
                for (int j = 0; j < 4; ++j) {
                    int co = pr * 16 + g * 4 + j;
                    float scale = 1.f / (1.f + __expf(-(accL[wt][j] + 2.f)));
                    float xv = bf2f(Xt[xt_off(r + 2, w + 1, co)]);
                    size_t xi = (((size_t)b * 64 + co) * 64 + h) * 64 + w;
                    out[xi] = scale * xv + accM[wt][j];
                    prod *= scale;
                }
            }
            ldacc += __logf(prod);
        }
        // no trailing barrier: next row writes Ct[(r+1)&1]
    }

    // ---- logdet partial for this strip ----
    #pragma unroll
    for (int off = 32; off; off >>= 1) ldacc += __shfl_down(ldacc, off);
    if (lane == 0) red[wv] = ldacc;
    __syncthreads();
    if (tid == 0) {
        float s = 0.f;
        #pragma unroll
        for (int i = 0; i < 8; ++i) s += red[i];
        row_ld[blk] = s;
    }
}

__global__ __launch_bounds__(64) void mcf_ldreduce(
    const float* __restrict__ row_ld, float* __restrict__ ldout)
{
    int b = blockIdx.x;
    int l = threadIdx.x;
    float v = (l < STRIPS) ? row_ld[b * STRIPS + l] : 0.f;
    #pragma unroll
    for (int off = 32; off; off >>= 1) v += __shfl_down(v, off);
    if (l == 0) ldout[b] = v;
}

extern "C" void kernel_launch(void* const* d_in, const int* in_sizes, int n_in,
                              void* d_out, int out_size, void* d_ws, size_t ws_size,
                              hipStream_t stream) {
    const float* x  = (const float*)d_in[0];
    const float* Wm = (const float*)d_in[1];
    const float* bm = (const float*)d_in[2];
    const float* W1 = (const float*)d_in[3];
    const float* b1 = (const float*)d_in[4];
    float* out = (float*)d_out;

    float* row_ld = (float*)d_ws;                                   // 1024 B
    unsigned short* WmR = (unsigned short*)((char*)d_ws + 8192);    // 196608 B
    unsigned short* W1b = WmR + 6 * 256 * 64;                       // 65536 B

    hipLaunchKernelGGL(mcf_prep, dim3(512), dim3(256), 0, stream,
                       Wm, W1, WmR, W1b);
    hipLaunchKernelGGL(mcf_mfma, dim3(NBLK), dim3(512), 0, stream,
                       x, WmR, bm, W1b, b1, out, row_ld);
    hipLaunchKernelGGL(mcf_ldreduce, dim3(BATCH), dim3(64), 0, stream,
                       row_ld, out + (size_t)BATCH * 64 * HDIM * WDIM);
}

// Round 16
// 89.541 us; speedup vs baseline: 1.3495x; 1.3495x over previous
//
#include <hip/hip_runtime.h>
#include <math.h>

// MaskedConvFlow — bf16 MFMA, 8-row strips, Ct double-buffered, pipelined.
// R16 = R14's EXACT tiling (R15's retile re-poisoned the allocator: spill +
// L2 thrash) with ONE change: inter-barrier region reordered to
//   G1(0); barrier; loop { G1(r+1); G2(r)+epilogue(r); barrier; }
// so the post-barrier code is G1's dense independent ds_read/MFMA stream
// (stalls hidden) and G2's short dependent chain fills G1's MFMA shadow.
// Buffer safety: G2(r) reads buf[r&1] (written before previous barrier);
// G1(r+1) writes buf[(r+1)&1] whose last reader G2(r-1) is fenced by the
// iter-(r-1) barrier. (512,2) only; min_waves>=3 hints are allocator poison.

#define BATCH 32
#define HDIM 64
#define WDIM 64
#define ROWS 8
#define STRIPS 8
#define NBLK (BATCH * STRIPS)   // 256
#define NSLOT 10                // input rows h0-2 .. h0+7
#define CT_LD 264               // 256 + 8 pad shorts (16B-aligned rows)

typedef __attribute__((ext_vector_type(8))) short short8;
typedef __attribute__((ext_vector_type(4))) float f32x4;

__device__ inline unsigned short f2bf(float f) {
    union { float f; unsigned int u; } v; v.f = f;
    unsigned int u = v.u;
    unsigned int r = u + 0x7FFFu + ((u >> 16) & 1u);   // RNE
    return (unsigned short)(r >> 16);
}

__device__ inline float bf2f(unsigned short s) {
    union { unsigned int u; float f; } v;
    v.u = ((unsigned int)s) << 16;
    return v.f;
}

// Xt element offset (shorts): chunk-XOR swizzle, conflict-free b128 reads
__device__ inline int xt_off(int slot, int wp, int ci) {
    return ((slot * 66 + wp) << 6) + ((((ci >> 3) ^ (wp & 7)) << 3) | (ci & 7));
}

// ---- prep: weight convert/repack ----
// WmR[((kh*3+kw)*256+co)*64+ci] = bf16(Wm[co][ci][kh][kw]); W1b[o][k] = bf16(W1)
__global__ __launch_bounds__(256) void mcf_prep(
    const float* __restrict__ Wm, const float* __restrict__ W1,
    unsigned short* __restrict__ WmR, unsigned short* __restrict__ W1b)
{
    int idx = blockIdx.x * 256 + threadIdx.x;     // grid covers 131072
    if (idx < 6 * 256 * 64) {
        int khkw = idx >> 14;
        int rem = idx & 16383;
        int co = rem >> 6;
        int ci = rem & 63;
        int kh = khkw / 3, kw = khkw % 3;
        WmR[idx] = f2bf(Wm[((co * 64 + ci) * 2 + kh) * 3 + kw]);
    } else {
        int i = idx - 6 * 256 * 64;
        W1b[i] = f2bf(W1[i]);
    }
}

// ---- GEMM1 for one output row r -> Cb (R14's exact tiling) ----
__device__ __forceinline__ void gemm1_row(
    int r, unsigned short* __restrict__ Cb,
    const unsigned short* __restrict__ Xt,
    const unsigned short* __restrict__ WmR,
    const float* __restrict__ bm,
    int wv, int col, int g)
{
    f32x4 acc[2][4];
    #pragma unroll
    for (int ct = 0; ct < 2; ++ct) {
        #pragma unroll
        for (int j = 0; j < 4; ++j) {
            float bv = bm[wv * 32 + ct * 16 + g * 4 + j];
            #pragma unroll
            for (int wt = 0; wt < 4; ++wt) acc[ct][wt][j] = bv;
        }
    }

    #pragma unroll
    for (int kh = 0; kh < 2; ++kh) {
        #pragma unroll
        for (int kw = 0; kw < 3; ++kw) {
            const unsigned short* wmk = WmR + ((kh * 3 + kw) << 14);
            #pragma unroll
            for (int ks = 0; ks < 2; ++ks) {
                short8 bfrag[4];
                #pragma unroll
                for (int wt = 0; wt < 4; ++wt) {
                    int wp = wt * 16 + col + kw;
                    bfrag[wt] = *reinterpret_cast<const short8*>(
                        &Xt[(((r + kh) * 66 + wp) << 6) + ((((ks * 4 + g) ^ (wp & 7)) << 3))]);
                }
                #pragma unroll
                for (int ct = 0; ct < 2; ++ct) {
                    short8 af = *reinterpret_cast<const short8*>(
                        &wmk[(wv * 32 + ct * 16 + col) * 64 + ks * 32 + g * 8]);
                    #pragma unroll
                    for (int wt = 0; wt < 4; ++wt)
                        acc[ct][wt] = __builtin_amdgcn_mfma_f32_16x16x32_bf16(
                            af, bfrag[wt], acc[ct][wt], 0, 0, 0);
                }
            }
        }
    }
    // relu -> bf16 -> Ct[w][co]
    #pragma unroll
    for (int ct = 0; ct < 2; ++ct) {
        int co_base = wv * 32 + ct * 16 + g * 4;
        #pragma unroll
        for (int wt = 0; wt < 4; ++wt) {
            int w = wt * 16 + col;
            unsigned short pk[4];
            #pragma unroll
            for (int j = 0; j < 4; ++j) pk[j] = f2bf(fmaxf(acc[ct][wt][j], 0.f));
            *reinterpret_cast<unsigned long long*>(&Cb[w * CT_LD + co_base]) =
                *reinterpret_cast<const unsigned long long*>(pk);
        }
    }
}

__global__ __launch_bounds__(512, 2) void mcf_mfma(
    const float* __restrict__ x,
    const unsigned short* __restrict__ WmR,
    const float* __restrict__ bm,
    const unsigned short* __restrict__ W1b,
    const float* __restrict__ b1,
    float* __restrict__ out, float* __restrict__ row_ld)
{
    __shared__ __align__(16) unsigned short Xt[NSLOT * 66 * 64];  // 84480 B
    __shared__ __align__(16) unsigned short Ct[2][64 * CT_LD];    // 67584 B
    __shared__ float red[8];

    const int blk = blockIdx.x;
    const int b = blk >> 3;
    const int h0 = (blk & 7) * ROWS;
    const int tid = threadIdx.x;
    const int lane = tid & 63;
    const int wv = tid >> 6;        // 0..7
    const int col = lane & 15;
    const int g = lane >> 4;

    // ---- zero pad wp=0 / wp=65 for all slots (NSLOT*128 entries, STRIDED) ----
    for (int l = tid; l < NSLOT * 128; l += 512) {
        int s = l >> 7, rr = l & 127;
        int wp = (rr >= 64) ? 65 : 0, ci = rr & 63;
        Xt[xt_off(s, wp, ci)] = 0;
    }
    // ---- stage NSLOT input rows (h0-2..h0+7), paired-bf16 ----
    #pragma unroll 4
    for (int it = 0; it < NSLOT * 4; ++it) {
        int idx = it * 512 + tid;       // pair idx: 64 w * 32 ci2 * NSLOT slots
        int w = idx & 63;
        int ci = ((idx >> 6) & 31) * 2;
        int slot = idx >> 11;           // 0..NSLOT-1
        int row = h0 - 2 + slot;
        float v0 = 0.f, v1 = 0.f;
        if (row >= 0) {
            const float* base = &x[(((size_t)b * 64 + ci) * 64 + row) * 64 + w];
            v0 = base[0];
            v1 = base[64 * 64];         // ci+1
        }
        unsigned int pk = (unsigned int)f2bf(v0) | ((unsigned int)f2bf(v1) << 16);
        *reinterpret_cast<unsigned int*>(&Xt[xt_off(slot, w + 1, ci)]) = pk;
    }
    __syncthreads();

    float ldacc = 0.f;

    // ---- software pipeline: G1(0); barrier; { G1(r+1); G2(r); barrier } ----
    gemm1_row(0, Ct[0], Xt, WmR, bm, wv, col, g);
    __syncthreads();

    #pragma unroll 1
    for (int r = 0; r < ROWS; ++r) {
        if (r + 1 < ROWS)
            gemm1_row(r + 1, Ct[(r + 1) & 1], Xt, WmR, bm, wv, col, g);

        // ---- GEMM2 + fused epilogue (row h0+r), R14 structure ----
        {
            const unsigned short* Cb = Ct[r & 1];
            const int pr = wv & 3;      // mu row-tile (ls = pr+4)
            const int wcg = wv >> 2;    // w-tile group
            f32x4 accM[2], accL[2];
            #pragma unroll
            for (int j = 0; j < 4; ++j) {
                float bmu = b1[pr * 16 + g * 4 + j];
                float bls = b1[64 + pr * 16 + g * 4 + j];
                accM[0][j] = bmu; accM[1][j] = bmu;
                accL[0][j] = bls; accL[1][j] = bls;
            }
            #pragma unroll
            for (int ks = 0; ks < 8; ++ks) {
                int kk = ks * 32 + g * 8;
                short8 bf2[2];
                #pragma unroll
                for (int wt = 0; wt < 2; ++wt) {
                    int w = (wcg * 2 + wt) * 16 + col;
                    bf2[wt] = *reinterpret_cast<const short8*>(&Cb[w * CT_LD + kk]);
                }
                int oA = pr * 16 + col;
                short8 aM = *reinterpret_cast<const short8*>(&W1b[oA * 256 + kk]);
                short8 aL = *reinterpret_cast<const short8*>(&W1b[(oA + 64) * 256 + kk]);
                #pragma unroll
                for (int wt = 0; wt < 2; ++wt) {
                    accM[wt] = __builtin_amdgcn_mfma_f32_16x16x32_bf16(aM, bf2[wt], accM[wt], 0, 0, 0);
                    accL[wt] = __builtin_amdgcn_mfma_f32_16x16x32_bf16(aL, bf2[wt], accL[wt], 0, 0, 0);
                }
            }
            int h = h0 + r;
            float prod = 1.f;
            #pragma unroll
            for (int wt = 0; wt < 2; ++wt) {
                int w = (wcg * 2 + wt) * 16 + col;
                #pragma unroll
                for (int j = 0; j < 4; ++j) {
                    int co = pr * 16 + g * 4 + j;
                    float scale = 1.f / (1.f + __expf(-(accL[wt][j] + 2.f)));
                    float xv = bf2f(Xt[xt_off(r + 2, w + 1, co)]);
                    size_t xi = (((size_t)b * 64 + co) * 64 + h) * 64 + w;
                    out[xi] = scale * xv + accM[wt][j];
                    prod *= scale;
                }
            }
            ldacc += __logf(prod);
        }
        __syncthreads();
    }

    // ---- logdet partial for this strip ----
    #pragma unroll
    for (int off = 32; off; off >>= 1) ldacc += __shfl_down(ldacc, off);
    if (lane == 0) red[wv] = ldacc;
    __syncthreads();
    if (tid == 0) {
        float s = 0.f;
        #pragma unroll
        for (int i = 0; i < 8; ++i) s += red[i];
        row_ld[blk] = s;
    }
}

__global__ __launch_bounds__(64) void mcf_ldreduce(
    const float* __restrict__ row_ld, float* __restrict__ ldout)
{
    int b = blockIdx.x;
    int l = threadIdx.x;
    float v = (l < STRIPS) ? row_ld[b * STRIPS + l] : 0.f;
    #pragma unroll
    for (int off = 32; off; off >>= 1) v += __shfl_down(v, off);
    if (l == 0) ldout[b] = v;
}

extern "C" void kernel_launch(void* const* d_in, const int* in_sizes, int n_in,
                              void* d_out, int out_size, void* d_ws, size_t ws_size,
                              hipStream_t stream) {
    const float* x  = (const float*)d_in[0];
    const float* Wm = (const float*)d_in[1];
    const float* bm = (const float*)d_in[2];
    const float* W1 = (const float*)d_in[3];
    const float* b1 = (const float*)d_in[4];
    float* out = (float*)d_out;

    float* row_ld = (float*)d_ws;                                   // 1024 B
    unsigned short* WmR = (unsigned short*)((char*)d_ws + 8192);    // 196608 B
    unsigned short* W1b = WmR + 6 * 256 * 64;                       // 65536 B

    hipLaunchKernelGGL(mcf_prep, dim3(512), dim3(256), 0, stream,
                       Wm, W1, WmR, W1b);
    hipLaunchKernelGGL(mcf_mfma, dim3(NBLK), dim3(512), 0, stream,
                       x, WmR, bm, W1b, b1, out, row_ld);
    hipLaunchKernelGGL(mcf_ldreduce, dim3(BATCH), dim3(64), 0, stream,
                       row_ld, out + (size_t)BATCH * 64 * HDIM * WDIM);
}

// Round 17
// 65.602 us; speedup vs baseline: 1.8420x; 1.3649x over previous
//
#include <hip/hip_runtime.h>
#include <math.h>

// MaskedConvFlow — bf16 MFMA, 8-row strips, Ct double-buffered.
// R17 = exact revert to R14, the best verified build (65.2us; FETCH 21MB /
// WRITE 33MB clean; VGPR 128; MfmaUtil 18.4).
// Session map: min_waves>=3 hints -> catastrophic spill (R4/R6/R7/R9);
// GEMM1 retile -> spill (R15); region reorder -> scheduler regression (R16).
// R14's tiling AND sequencing are load-bearing for this allocator.

#define BATCH 32
#define HDIM 64
#define WDIM 64
#define ROWS 8
#define STRIPS 8
#define NBLK (BATCH * STRIPS)   // 256
#define NSLOT 10                // input rows h0-2 .. h0+7
#define CT_LD 264               // 256 + 8 pad shorts (16B-aligned rows)

typedef __attribute__((ext_vector_type(8))) short short8;
typedef __attribute__((ext_vector_type(4))) float f32x4;

__device__ inline unsigned short f2bf(float f) {
    union { float f; unsigned int u; } v; v.f = f;
    unsigned int u = v.u;
    unsigned int r = u + 0x7FFFu + ((u >> 16) & 1u);   // RNE
    return (unsigned short)(r >> 16);
}

__device__ inline float bf2f(unsigned short s) {
    union { unsigned int u; float f; } v;
    v.u = ((unsigned int)s) << 16;
    return v.f;
}

// Xt element offset (shorts): chunk-XOR swizzle, conflict-free b128 reads
__device__ inline int xt_off(int slot, int wp, int ci) {
    return ((slot * 66 + wp) << 6) + ((((ci >> 3) ^ (wp & 7)) << 3) | (ci & 7));
}

// ---- prep: weight convert/repack ----
// WmR[((kh*3+kw)*256+co)*64+ci] = bf16(Wm[co][ci][kh][kw]); W1b[o][k] = bf16(W1)
__global__ __launch_bounds__(256) void mcf_prep(
    const float* __restrict__ Wm, const float* __restrict__ W1,
    unsigned short* __restrict__ WmR, unsigned short* __restrict__ W1b)
{
    int idx = blockIdx.x * 256 + threadIdx.x;     // grid covers 131072
    if (idx < 6 * 256 * 64) {
        int khkw = idx >> 14;
        int rem = idx & 16383;
        int co = rem >> 6;
        int ci = rem & 63;
        int kh = khkw / 3, kw = khkw % 3;
        WmR[idx] = f2bf(Wm[((co * 64 + ci) * 2 + kh) * 3 + kw]);
    } else {
        int i = idx - 6 * 256 * 64;
        W1b[i] = f2bf(W1[i]);
    }
}

__global__ __launch_bounds__(512, 2) void mcf_mfma(
    const float* __restrict__ x,
    const unsigned short* __restrict__ WmR,
    const float* __restrict__ bm,
    const unsigned short* __restrict__ W1b,
    const float* __restrict__ b1,
    float* __restrict__ out, float* __restrict__ row_ld)
{
    __shared__ __align__(16) unsigned short Xt[NSLOT * 66 * 64];  // 84480 B
    __shared__ __align__(16) unsigned short Ct[2][64 * CT_LD];    // 67584 B
    __shared__ float red[8];

    const int blk = blockIdx.x;
    const int b = blk >> 3;
    const int h0 = (blk & 7) * ROWS;
    const int tid = threadIdx.x;
    const int lane = tid & 63;
    const int wv = tid >> 6;        // 0..7
    const int col = lane & 15;
    const int g = lane >> 4;

    // ---- zero pad wp=0 / wp=65 for all slots (NSLOT*128 entries, STRIDED) ----
    for (int l = tid; l < NSLOT * 128; l += 512) {
        int s = l >> 7, rr = l & 127;
        int wp = (rr >= 64) ? 65 : 0, ci = rr & 63;
        Xt[xt_off(s, wp, ci)] = 0;
    }
    // ---- stage NSLOT input rows (h0-2..h0+7), paired-bf16 ----
    #pragma unroll 4
    for (int it = 0; it < NSLOT * 4; ++it) {
        int idx = it * 512 + tid;       // pair idx: 64 w * 32 ci2 * NSLOT slots
        int w = idx & 63;
        int ci = ((idx >> 6) & 31) * 2;
        int slot = idx >> 11;           // 0..NSLOT-1
        int row = h0 - 2 + slot;
        float v0 = 0.f, v1 = 0.f;
        if (row >= 0) {
            const float* base = &x[(((size_t)b * 64 + ci) * 64 + row) * 64 + w];
            v0 = base[0];
            v1 = base[64 * 64];         // ci+1
        }
        unsigned int pk = (unsigned int)f2bf(v0) | ((unsigned int)f2bf(v1) << 16);
        *reinterpret_cast<unsigned int*>(&Xt[xt_off(slot, w + 1, ci)]) = pk;
    }
    __syncthreads();

    float ldacc = 0.f;

    #pragma unroll 1
    for (int r = 0; r < ROWS; ++r) {
        unsigned short* Cb = Ct[r & 1];

        // ---- GEMM1 (R5 structure): acc[2][4], 6 shifted (kh,kw) GEMMs ----
        f32x4 acc[2][4];
        #pragma unroll
        for (int ct = 0; ct < 2; ++ct) {
            #pragma unroll
            for (int j = 0; j < 4; ++j) {
                float bv = bm[wv * 32 + ct * 16 + g * 4 + j];
                #pragma unroll
                for (int wt = 0; wt < 4; ++wt) acc[ct][wt][j] = bv;
            }
        }

        #pragma unroll
        for (int kh = 0; kh < 2; ++kh) {
            #pragma unroll
            for (int kw = 0; kw < 3; ++kw) {
                const unsigned short* wmk = WmR + ((kh * 3 + kw) << 14);
                #pragma unroll
                for (int ks = 0; ks < 2; ++ks) {
                    short8 bfrag[4];
                    #pragma unroll
                    for (int wt = 0; wt < 4; ++wt) {
                        int wp = wt * 16 + col + kw;
                        bfrag[wt] = *reinterpret_cast<const short8*>(
                            &Xt[(((r + kh) * 66 + wp) << 6) + ((((ks * 4 + g) ^ (wp & 7)) << 3))]);
                    }
                    #pragma unroll
                    for (int ct = 0; ct < 2; ++ct) {
                        short8 af = *reinterpret_cast<const short8*>(
                            &wmk[(wv * 32 + ct * 16 + col) * 64 + ks * 32 + g * 8]);
                        #pragma unroll
                        for (int wt = 0; wt < 4; ++wt)
                            acc[ct][wt] = __builtin_amdgcn_mfma_f32_16x16x32_bf16(
                                af, bfrag[wt], acc[ct][wt], 0, 0, 0);
                    }
                }
            }
        }
        // relu -> bf16 -> Ct[w][co]
        #pragma unroll
        for (int ct = 0; ct < 2; ++ct) {
            int co_base = wv * 32 + ct * 16 + g * 4;
            #pragma unroll
            for (int wt = 0; wt < 4; ++wt) {
                int w = wt * 16 + col;
                unsigned short pk[4];
                #pragma unroll
                for (int j = 0; j < 4; ++j) pk[j] = f2bf(fmaxf(acc[ct][wt][j], 0.f));
                *reinterpret_cast<unsigned long long*>(&Cb[w * CT_LD + co_base]) =
                    *reinterpret_cast<const unsigned long long*>(pk);
            }
        }
        __syncthreads();   // Ct[r&1] ready — only barrier this row

        // ---- GEMM2 + fused epilogue (row h0+r) ----
        {
            const int pr = wv & 3;      // mu row-tile (ls = pr+4)
            const int wcg = wv >> 2;    // w-tile group
            f32x4 accM[2], accL[2];
            #pragma unroll
            for (int j = 0; j < 4; ++j) {
                float bmu = b1[pr * 16 + g * 4 + j];
                float bls = b1[64 + pr * 16 + g * 4 + j];
                accM[0][j] = bmu; accM[1][j] = bmu;
                accL[0][j] = bls; accL[1][j] = bls;
            }
            #pragma unroll
            for (int ks = 0; ks < 8; ++ks) {
                int kk = ks * 32 + g * 8;
                short8 bf2[2];
                #pragma unroll
                for (int wt = 0; wt < 2; ++wt) {
                    int w = (wcg * 2 + wt) * 16 + col;
                    bf2[wt] = *reinterpret_cast<const short8*>(&Cb[w * CT_LD + kk]);
                }
                int oA = pr * 16 + col;
                short8 aM = *reinterpret_cast<const short8*>(&W1b[oA * 256 + kk]);
                short8 aL = *reinterpret_cast<const short8*>(&W1b[(oA + 64) * 256 + kk]);
                #pragma unroll
                for (int wt = 0; wt < 2; ++wt) {
                    accM[wt] = __builtin_amdgcn_mfma_f32_16x16x32_bf16(aM, bf2[wt], accM[wt], 0, 0, 0);
                    accL[wt] = __builtin_amdgcn_mfma_f32_16x16x32_bf16(aL, bf2[wt], accL[wt], 0, 0, 0);
                }
            }
            int h = h0 + r;
            float prod = 1.f;
            #pragma unroll
            for (int wt = 0; wt < 2; ++wt) {
                int w = (wcg * 2 + wt) * 16 + col;
                #pragma unroll
                for (int j = 0; j < 4; ++j) {
                    int co = pr * 16 + g * 4 + j;
                    float scale = 1.f / (1.f + __expf(-(accL[wt][j] + 2.f)));
                    // x from LDS (bf16, staged): slot r+2, wp w+1, ci co
                    float xv = bf2f(Xt[xt_off(r + 2, w + 1, co)]);
                    size_t xi = (((size_t)b * 64 + co) * 64 + h) * 64 + w;
                    out[xi] = scale * xv + accM[wt][j];
                    prod *= scale;
                }
            }
            ldacc += __logf(prod);
        }
        // no trailing barrier: next row writes Ct[(r+1)&1]
    }

    // ---- logdet partial for this strip ----
    #pragma unroll
    for (int off = 32; off; off >>= 1) ldacc += __shfl_down(ldacc, off);
    if (lane == 0) red[wv] = ldacc;
    __syncthreads();
    if (tid == 0) {
        float s = 0.f;
        #pragma unroll
        for (int i = 0; i < 8; ++i) s += red[i];
        row_ld[blk] = s;
    }
}

__global__ __launch_bounds__(64) void mcf_ldreduce(
    const float* __restrict__ row_ld, float* __restrict__ ldout)
{
    int b = blockIdx.x;
    int l = threadIdx.x;
    float v = (l < STRIPS) ? row_ld[b * STRIPS + l] : 0.f;
    #pragma unroll
    for (int off = 32; off; off >>= 1) v += __shfl_down(v, off);
    if (l == 0) ldout[b] = v;
}

extern "C" void kernel_launch(void* const* d_in, const int* in_sizes, int n_in,
                              void* d_out, int out_size, void* d_ws, size_t ws_size,
                              hipStream_t stream) {
    const float* x  = (const float*)d_in[0];
    const float* Wm = (const float*)d_in[1];
    const float* bm = (const float*)d_in[2];
    const float* W1 = (const float*)d_in[3];
    const float* b1 = (const float*)d_in[4];
    float* out = (float*)d_out;

    float* row_ld = (float*)d_ws;                                   // 1024 B
    unsigned short* WmR = (unsigned short*)((char*)d_ws + 8192);    // 196608 B
    unsigned short* W1b = WmR + 6 * 256 * 64;                       // 65536 B

    hipLaunchKernelGGL(mcf_prep, dim3(512), dim3(256), 0, stream,
                       Wm, W1, WmR, W1b);
    hipLaunchKernelGGL(mcf_mfma, dim3(NBLK), dim3(512), 0, stream,
                       x, WmR, bm, W1b, b1, out, row_ld);
    hipLaunchKernelGGL(mcf_ldreduce, dim3(BATCH), dim3(64), 0, stream,
                       row_ld, out + (size_t)BATCH * 64 * HDIM * WDIM);
}